// Round 12
// baseline (46.279 us; speedup 1.0000x reference)
//
#include <hip/hip_runtime.h>
#include <hip/hip_bf16.h>

#define F_IN 256
#define NQ   4096
#define NK   4096
#define MAXC 16

// ---------------------------------------------------------------------------
// Round 12: output dtype fixed to FLOAT32 (root cause of rounds 1-10).
// Dict-order binding (confirmed by sizes, content probe, and round-11 fault).
// Faithful one-hot attention: f32 presence gaps (min distinct-f32 gap in
// [0.5,1) is 6e-8 -> mask gap >= 6e24 >> 416) force softmax weight zero for
// every key except the exact-max-presence set; exact ties are softmaxed over
// qk*0.25 (mask cancels). When the argmax is unique (C==1) the weight is
// exactly 1 and q/k projections cancel entirely -> skip them.
// ---------------------------------------------------------------------------
__global__ __launch_bounds__(256) void attn_onehot(
    const float* __restrict__ queries, const float* __restrict__ keys,
    const float* __restrict__ values,  const float* __restrict__ presence,
    const float* __restrict__ Wq, const float* __restrict__ bq,
    const float* __restrict__ Wk, const float* __restrict__ bk,
    const float* __restrict__ Wv, const float* __restrict__ bv,
    const float* __restrict__ Wo, const float* __restrict__ bo,
    float* __restrict__ out)
{
    const int t  = threadIdx.x;
    const int h  = t >> 4;
    const int qi = t & 15;
    const int q0 = blockIdx.x * 16;

    __shared__ float redA[256];
    __shared__ float XH[16][260];
    __shared__ float WoS[4096];
    __shared__ int   candS[MAXC];
    __shared__ int   ncandS;
    __shared__ float pmaxS;

    // stage Wo (256x16)
    for (int i = t; i < 1024; i += 256)
        *reinterpret_cast<float4*>(&WoS[i * 4]) =
            *reinterpret_cast<const float4*>(&Wo[i * 4]);

    // pmax over presence
    float mx = -1e30f;
    for (int i = t; i < NK; i += 256) mx = fmaxf(mx, presence[i]);
    redA[t] = mx;
    __syncthreads();
    for (int s = 128; s > 0; s >>= 1) {
        if (t < s) redA[t] = fmaxf(redA[t], redA[t + s]);
        __syncthreads();
    }
    if (t == 0) { pmaxS = redA[0]; ncandS = 0; }
    __syncthreads();
    const float pmax = pmaxS;

    // exact-tie candidate set (deterministically sorted)
    for (int i = t; i < NK; i += 256) {
        if (presence[i] == pmax) {
            int slot = atomicAdd(&ncandS, 1);
            if (slot < MAXC) candS[slot] = i;
        }
    }
    __syncthreads();
    if (t == 0) {
        int n = ncandS < MAXC ? ncandS : MAXC;
        for (int a = 0; a < n; ++a)
            for (int b = a + 1; b < n; ++b)
                if (candS[b] < candS[a]) { int tmp = candS[a]; candS[a] = candS[b]; candS[b] = tmp; }
    }
    __syncthreads();
    const int C = ncandS < MAXC ? ncandS : MAXC;

    float wgt[MAXC];
    float inv;
    if (C == 1) {
        wgt[0] = 1.0f;
        inv = 1.0f;
    } else {
        // q projection (thread: q-row q0+qi, head h)
        float qr[16];
        #pragma unroll
        for (int d = 0; d < 16; ++d) qr[d] = bq[h * 16 + d];
        for (int c = 0; c < F_IN; ++c) {
            const float x = queries[(size_t)(q0 + qi) * F_IN + c];
            const float* wr = &Wq[(size_t)c * F_IN + h * 16];
            #pragma unroll
            for (int d = 0; d < 16; ++d) qr[d] = fmaf(x, wr[d], qr[d]);
        }
        // candidate scores (shared mask cancels)
        float sarr[MAXC];
        for (int ci = 0; ci < C; ++ci) {
            const int k = candS[ci];
            float kr[16];
            #pragma unroll
            for (int d = 0; d < 16; ++d) kr[d] = bk[h * 16 + d];
            for (int c = 0; c < F_IN; ++c) {
                const float x = keys[(size_t)k * F_IN + c];
                const float* wr = &Wk[(size_t)c * F_IN + h * 16];
                #pragma unroll
                for (int d = 0; d < 16; ++d) kr[d] = fmaf(x, wr[d], kr[d]);
            }
            float qk = 0.f;
            #pragma unroll
            for (int d = 0; d < 16; ++d) qk = fmaf(qr[d], kr[d], qk);
            sarr[ci] = qk * 0.25f;
        }
        float m = -INFINITY;
        for (int ci = 0; ci < C; ++ci) m = fmaxf(m, sarr[ci]);
        float l = 0.f;
        for (int ci = 0; ci < C; ++ci) { wgt[ci] = __expf(sarr[ci] - m); l += wgt[ci]; }
        inv = 1.0f / l;
    }

    // weighted, on-demand-projected V rows
    float o[16] = {};
    for (int ci = 0; ci < C; ++ci) {
        const int k = candS[ci];
        float vr[16];
        #pragma unroll
        for (int d = 0; d < 16; ++d) vr[d] = bv[h * 16 + d];
        for (int c = 0; c < F_IN; ++c) {
            const float x = values[(size_t)k * F_IN + c];
            const float* wr = &Wv[(size_t)c * F_IN + h * 16];
            #pragma unroll
            for (int d = 0; d < 16; ++d) vr[d] = fmaf(x, wr[d], vr[d]);
        }
        const float ww = wgt[ci] * inv;
        #pragma unroll
        for (int d = 0; d < 16; ++d) o[d] = fmaf(ww, vr[d], o[d]);
    }

    // heads -> LDS -> @Wo -> f32 store
    __syncthreads();
    #pragma unroll
    for (int d = 0; d < 16; ++d) XH[qi][h * 16 + d] = o[d];
    __syncthreads();

    const int nl = t >> 4, j = t & 15;
    float acc = bo[j];
    #pragma unroll 8
    for (int c = 0; c < F_IN; ++c)
        acc = fmaf(XH[nl][c], WoS[c * 16 + j], acc);
    out[(size_t)(q0 + nl) * 16 + j] = acc;   // FLOAT32 output
}

// ---------------------------------------------------------------------------
extern "C" void kernel_launch(void* const* d_in, const int* in_sizes, int n_in,
                              void* d_out, int out_size, void* d_ws, size_t ws_size,
                              hipStream_t stream) {
    const float* queries  = (const float*)d_in[0];
    const float* keys     = (const float*)d_in[1];
    const float* values   = (const float*)d_in[2];
    const float* presence = (const float*)d_in[3];
    const float* Wq = (const float*)d_in[4];
    const float* bq = (const float*)d_in[5];
    const float* Wk = (const float*)d_in[6];
    const float* bk = (const float*)d_in[7];
    const float* Wv = (const float*)d_in[8];
    const float* bv = (const float*)d_in[9];
    const float* Wo = (const float*)d_in[10];
    const float* bo = (const float*)d_in[11];
    float* out = (float*)d_out;

    attn_onehot<<<NQ / 16, 256, 0, stream>>>(
        queries, keys, values, presence, Wq, bq, Wk, bk, Wv, bv, Wo, bo, out);
}

// Round 13
// 18.115 us; speedup vs baseline: 2.5548x; 2.5548x over previous
//
#include <hip/hip_runtime.h>
#include <hip/hip_bf16.h>

#define F_IN 256
#define NQ   4096
#define NK   4096
#define MAXC 16

// ---------------------------------------------------------------------------
// Round 13: eliminate the rank-1 redundancy.
// Proven facts: f32 presence gaps make softmax exactly one-hot at the unique
// argmax (round 12 absmax == 0.0 on the C==1 path); output rows identical.
// C==1 path (the live one): each block computes head = values[k*]@Wv + bv
// with ONE thread per feature (same fma chain order as round 12 -> bitwise
// identical), folds Wo/bo on 16 threads, stores its 16 rows (1 KB coalesced).
// C>1 fallback: round-12 per-(h,qi) code, mathematically faithful (softmax
// over exact ties; expf underflow matches numpy exactly).
// ---------------------------------------------------------------------------
__global__ __launch_bounds__(256) void attn_onehot(
    const float* __restrict__ queries, const float* __restrict__ keys,
    const float* __restrict__ values,  const float* __restrict__ presence,
    const float* __restrict__ Wq, const float* __restrict__ bq,
    const float* __restrict__ Wk, const float* __restrict__ bk,
    const float* __restrict__ Wv, const float* __restrict__ bv,
    const float* __restrict__ Wo, const float* __restrict__ bo,
    float* __restrict__ out)
{
    const int t  = threadIdx.x;
    const int h  = t >> 4;
    const int qi = t & 15;
    const int q0 = blockIdx.x * 16;

    __shared__ float redA[256];
    __shared__ float XH[16][260];
    __shared__ float WoS[4096];
    __shared__ float hvS[256];
    __shared__ float rS[16];
    __shared__ int   candS[MAXC];
    __shared__ int   ncandS;
    __shared__ float pmaxS;

    // ---- pmax over presence (float4 scan; max is order-insensitive) ----
    {
        const float4* p4 = reinterpret_cast<const float4*>(presence);
        float mx = -1e30f;
        #pragma unroll
        for (int i = 0; i < 4; ++i) {
            const float4 v = p4[i * 256 + t];
            mx = fmaxf(mx, fmaxf(fmaxf(v.x, v.y), fmaxf(v.z, v.w)));
        }
        redA[t] = mx;
    }
    __syncthreads();
    for (int s = 128; s > 0; s >>= 1) {
        if (t < s) redA[t] = fmaxf(redA[t], redA[t + s]);
        __syncthreads();
    }
    if (t == 0) { pmaxS = redA[0]; ncandS = 0; }
    __syncthreads();
    const float pmax = pmaxS;

    // ---- exact-tie candidate set (deterministically sorted) ----
    for (int i = t; i < NK; i += 256) {
        if (presence[i] == pmax) {
            int slot = atomicAdd(&ncandS, 1);
            if (slot < MAXC) candS[slot] = i;
        }
    }
    __syncthreads();
    if (t == 0) {
        int n = ncandS < MAXC ? ncandS : MAXC;
        for (int a = 0; a < n; ++a)
            for (int b = a + 1; b < n; ++b)
                if (candS[b] < candS[a]) { int tmp = candS[a]; candS[a] = candS[b]; candS[b] = tmp; }
    }
    __syncthreads();
    const int C = ncandS < MAXC ? ncandS : MAXC;

    if (C == 1) {
        // ---- live path: weight is exactly 1.0; q/k projections cancel ----
        const int k = candS[0];
        // head feature f = t : same fma chain order as round 12 -> same bits
        {
            const float* vrow = &values[(size_t)k * F_IN];
            float acc = bv[t];
            #pragma unroll 8
            for (int c = 0; c < F_IN; ++c)
                acc = fmaf(vrow[c], Wv[(size_t)c * F_IN + t], acc);
            hvS[t] = acc;
        }
        __syncthreads();
        if (t < 16) {
            float r = bo[t];
            #pragma unroll 8
            for (int f = 0; f < F_IN; ++f)
                r = fmaf(hvS[f], Wo[(size_t)f * 16 + t], r);
            rS[t] = r;
        }
        __syncthreads();
        // 16 identical rows for this block: flat base = q0*16 = bid*256
        out[(size_t)q0 * 16 + t] = rS[t & 15];
        return;
    }

    // ======================= general fallback (C > 1) =======================
    // stage Wo (256x16)
    for (int i = t; i < 1024; i += 256)
        *reinterpret_cast<float4*>(&WoS[i * 4]) =
            *reinterpret_cast<const float4*>(&Wo[i * 4]);
    __syncthreads();

    // q projection (thread: q-row q0+qi, head h)
    float qr[16];
    #pragma unroll
    for (int d = 0; d < 16; ++d) qr[d] = bq[h * 16 + d];
    for (int c = 0; c < F_IN; ++c) {
        const float x = queries[(size_t)(q0 + qi) * F_IN + c];
        const float* wr = &Wq[(size_t)c * F_IN + h * 16];
        #pragma unroll
        for (int d = 0; d < 16; ++d) qr[d] = fmaf(x, wr[d], qr[d]);
    }

    // candidate scores (shared mask cancels)
    float sarr[MAXC];
    for (int ci = 0; ci < C; ++ci) {
        const int k = candS[ci];
        float kr[16];
        #pragma unroll
        for (int d = 0; d < 16; ++d) kr[d] = bk[h * 16 + d];
        for (int c = 0; c < F_IN; ++c) {
            const float x = keys[(size_t)k * F_IN + c];
            const float* wr = &Wk[(size_t)c * F_IN + h * 16];
            #pragma unroll
            for (int d = 0; d < 16; ++d) kr[d] = fmaf(x, wr[d], kr[d]);
        }
        float qk = 0.f;
        #pragma unroll
        for (int d = 0; d < 16; ++d) qk = fmaf(qr[d], kr[d], qk);
        sarr[ci] = qk * 0.25f;
    }
    float m = -INFINITY;
    for (int ci = 0; ci < C; ++ci) m = fmaxf(m, sarr[ci]);
    float wgt[MAXC];
    float l = 0.f;
    for (int ci = 0; ci < C; ++ci) { wgt[ci] = __expf(sarr[ci] - m); l += wgt[ci]; }
    const float inv = 1.0f / l;

    // weighted, on-demand-projected V rows
    float o[16] = {};
    for (int ci = 0; ci < C; ++ci) {
        const int k = candS[ci];
        float vr[16];
        #pragma unroll
        for (int d = 0; d < 16; ++d) vr[d] = bv[h * 16 + d];
        for (int c = 0; c < F_IN; ++c) {
            const float x = values[(size_t)k * F_IN + c];
            const float* wr = &Wv[(size_t)c * F_IN + h * 16];
            #pragma unroll
            for (int d = 0; d < 16; ++d) vr[d] = fmaf(x, wr[d], vr[d]);
        }
        const float ww = wgt[ci] * inv;
        #pragma unroll
        for (int d = 0; d < 16; ++d) o[d] = fmaf(ww, vr[d], o[d]);
    }

    // heads -> LDS -> @Wo -> f32 store
    __syncthreads();
    #pragma unroll
    for (int d = 0; d < 16; ++d) XH[qi][h * 16 + d] = o[d];
    __syncthreads();

    const int nl = t >> 4, j = t & 15;
    float acc = bo[j];
    #pragma unroll 8
    for (int c = 0; c < F_IN; ++c)
        acc = fmaf(XH[nl][c], WoS[c * 16 + j], acc);
    out[(size_t)(q0 + nl) * 16 + j] = acc;
}

// ---------------------------------------------------------------------------
extern "C" void kernel_launch(void* const* d_in, const int* in_sizes, int n_in,
                              void* d_out, int out_size, void* d_ws, size_t ws_size,
                              hipStream_t stream) {
    const float* queries  = (const float*)d_in[0];
    const float* keys     = (const float*)d_in[1];
    const float* values   = (const float*)d_in[2];
    const float* presence = (const float*)d_in[3];
    const float* Wq = (const float*)d_in[4];
    const float* bq = (const float*)d_in[5];
    const float* Wk = (const float*)d_in[6];
    const float* bk = (const float*)d_in[7];
    const float* Wv = (const float*)d_in[8];
    const float* bv = (const float*)d_in[9];
    const float* Wo = (const float*)d_in[10];
    const float* bo = (const float*)d_in[11];
    float* out = (float*)d_out;

    attn_onehot<<<NQ / 16, 256, 0, stream>>>(
        queries, keys, values, presence, Wq, bq, Wk, bk, Wv, bv, Wo, bo, out);
}

// Round 14
// 14.433 us; speedup vs baseline: 3.2065x; 1.2551x over previous
//
#include <hip/hip_runtime.h>
#include <hip/hip_bf16.h>

#define F_IN 256
#define NQ   4096
#define NK   4096
#define MAXC 16

// ws layout: wsi[0]=C, wsi[1..16]=candS; wsf[32..47]=rS[16]
// ---------------------------------------------------------------------------
// Kernel A (1 block): presence argmax + exact-tie set; if unique (C==1,
// the live path: softmax weight is exactly 1, q/k projections cancel),
// compute rS = (values[k*]@Wv + bv)@Wo + bo once and stash it in d_ws.
// ---------------------------------------------------------------------------
__global__ __launch_bounds__(256) void compute_head(
    const float* __restrict__ values, const float* __restrict__ presence,
    const float* __restrict__ Wv, const float* __restrict__ bv,
    const float* __restrict__ Wo, const float* __restrict__ bo,
    int* __restrict__ wsi, float* __restrict__ wsf)
{
    const int t = threadIdx.x;

    __shared__ float redA[256];
    __shared__ float hvS[256];
    __shared__ int   candS[MAXC];
    __shared__ int   ncandS;
    __shared__ float pmaxS;

    // one pass of presence into registers (float4, coalesced)
    float4 pv[4];
    {
        const float4* p4 = reinterpret_cast<const float4*>(presence);
        float mx = -1e30f;
        #pragma unroll
        for (int i = 0; i < 4; ++i) {
            pv[i] = p4[i * 256 + t];
            mx = fmaxf(mx, fmaxf(fmaxf(pv[i].x, pv[i].y), fmaxf(pv[i].z, pv[i].w)));
        }
        redA[t] = mx;
    }
    __syncthreads();
    for (int s = 128; s > 0; s >>= 1) {
        if (t < s) redA[t] = fmaxf(redA[t], redA[t + s]);
        __syncthreads();
    }
    if (t == 0) { pmaxS = redA[0]; ncandS = 0; }
    __syncthreads();
    const float pmax = pmaxS;

    // tie set from registers (no re-read)
    #pragma unroll
    for (int i = 0; i < 4; ++i) {
        const int base = (i * 256 + t) * 4;
        const float e[4] = {pv[i].x, pv[i].y, pv[i].z, pv[i].w};
        #pragma unroll
        for (int j = 0; j < 4; ++j) {
            if (e[j] == pmax) {
                int slot = atomicAdd(&ncandS, 1);
                if (slot < MAXC) candS[slot] = base + j;
            }
        }
    }
    __syncthreads();
    const int C = ncandS < MAXC ? ncandS : MAXC;
    if (t == 0) {
        int n = C;
        for (int a = 0; a < n; ++a)
            for (int b = a + 1; b < n; ++b)
                if (candS[b] < candS[a]) { int tmp = candS[a]; candS[a] = candS[b]; candS[b] = tmp; }
        wsi[0] = ncandS;
        for (int a = 0; a < MAXC; ++a) wsi[1 + a] = (a < n) ? candS[a] : 0;
    }
    __syncthreads();
    if (C != 1) return;   // fallback kernel handles the general case

    // hv[t] = bv[t] + values[k*,:] @ Wv[:,t]  (4-way split accumulators)
    const int k = candS[0];
    {
        const float* vrow = &values[(size_t)k * F_IN];
        float a0 = 0.f, a1 = 0.f, a2 = 0.f, a3 = 0.f;
        #pragma unroll 4
        for (int c = 0; c < F_IN; c += 4) {
            a0 = fmaf(vrow[c + 0], Wv[(size_t)(c + 0) * F_IN + t], a0);
            a1 = fmaf(vrow[c + 1], Wv[(size_t)(c + 1) * F_IN + t], a1);
            a2 = fmaf(vrow[c + 2], Wv[(size_t)(c + 2) * F_IN + t], a2);
            a3 = fmaf(vrow[c + 3], Wv[(size_t)(c + 3) * F_IN + t], a3);
        }
        hvS[t] = bv[t] + ((a0 + a1) + (a2 + a3));
    }
    __syncthreads();

    // rS[j] = bo[j] + sum_f hvS[f]*Wo[f][j], parallel over 16 f-groups
    {
        const int j = t & 15, g = t >> 4;
        float part = 0.f;
        #pragma unroll
        for (int f = g * 16; f < g * 16 + 16; ++f)
            part = fmaf(hvS[f], Wo[(size_t)f * 16 + j], part);
        redA[t] = part;
    }
    __syncthreads();
    for (int s = 128; s >= 16; s >>= 1) {
        if (t < s) redA[t] += redA[t + s];
        __syncthreads();
    }
    if (t < 16) wsf[32 + t] = redA[t] + bo[t];
}

// ---------------------------------------------------------------------------
// Kernel B (256 blocks): C==1 -> broadcast the 16 cached values to all 4096
// rows (1 KB coalesced store per block). C>1 -> full faithful fallback
// (round-13 logic; exact-tie softmax; never taken on this data).
// ---------------------------------------------------------------------------
__global__ __launch_bounds__(256) void write_out(
    const float* __restrict__ queries, const float* __restrict__ keys,
    const float* __restrict__ values,
    const float* __restrict__ Wq, const float* __restrict__ bq,
    const float* __restrict__ Wk, const float* __restrict__ bk,
    const float* __restrict__ Wv, const float* __restrict__ bv,
    const float* __restrict__ Wo, const float* __restrict__ bo,
    const int* __restrict__ wsi, const float* __restrict__ wsf,
    float* __restrict__ out)
{
    const int t  = threadIdx.x;
    const int q0 = blockIdx.x * 16;
    const int C  = wsi[0] < MAXC ? wsi[0] : MAXC;

    if (C == 1) {
        out[(size_t)q0 * 16 + t] = wsf[32 + (t & 15)];
        return;
    }

    // ======================= general fallback (C > 1) =======================
    const int h  = t >> 4;
    const int qi = t & 15;

    __shared__ float XH[16][260];
    __shared__ float WoS[4096];
    __shared__ int   candS[MAXC];

    if (t < MAXC) candS[t] = wsi[1 + t];
    for (int i = t; i < 1024; i += 256)
        *reinterpret_cast<float4*>(&WoS[i * 4]) =
            *reinterpret_cast<const float4*>(&Wo[i * 4]);
    __syncthreads();

    float qr[16];
    #pragma unroll
    for (int d = 0; d < 16; ++d) qr[d] = bq[h * 16 + d];
    for (int c = 0; c < F_IN; ++c) {
        const float x = queries[(size_t)(q0 + qi) * F_IN + c];
        const float* wr = &Wq[(size_t)c * F_IN + h * 16];
        #pragma unroll
        for (int d = 0; d < 16; ++d) qr[d] = fmaf(x, wr[d], qr[d]);
    }

    float sarr[MAXC];
    for (int ci = 0; ci < C; ++ci) {
        const int k = candS[ci];
        float kr[16];
        #pragma unroll
        for (int d = 0; d < 16; ++d) kr[d] = bk[h * 16 + d];
        for (int c = 0; c < F_IN; ++c) {
            const float x = keys[(size_t)k * F_IN + c];
            const float* wr = &Wk[(size_t)c * F_IN + h * 16];
            #pragma unroll
            for (int d = 0; d < 16; ++d) kr[d] = fmaf(x, wr[d], kr[d]);
        }
        float qk = 0.f;
        #pragma unroll
        for (int d = 0; d < 16; ++d) qk = fmaf(qr[d], kr[d], qk);
        sarr[ci] = qk * 0.25f;
    }
    float m = -INFINITY;
    for (int ci = 0; ci < C; ++ci) m = fmaxf(m, sarr[ci]);
    float wgt[MAXC];
    float l = 0.f;
    for (int ci = 0; ci < C; ++ci) { wgt[ci] = __expf(sarr[ci] - m); l += wgt[ci]; }
    const float inv = 1.0f / l;

    float o[16] = {};
    for (int ci = 0; ci < C; ++ci) {
        const int k = candS[ci];
        float vr[16];
        #pragma unroll
        for (int d = 0; d < 16; ++d) vr[d] = bv[h * 16 + d];
        for (int c = 0; c < F_IN; ++c) {
            const float x = values[(size_t)k * F_IN + c];
            const float* wr = &Wv[(size_t)c * F_IN + h * 16];
            #pragma unroll
            for (int d = 0; d < 16; ++d) vr[d] = fmaf(x, wr[d], vr[d]);
        }
        const float ww = wgt[ci] * inv;
        #pragma unroll
        for (int d = 0; d < 16; ++d) o[d] = fmaf(ww, vr[d], o[d]);
    }

    __syncthreads();
    #pragma unroll
    for (int d = 0; d < 16; ++d) XH[qi][h * 16 + d] = o[d];
    __syncthreads();

    const int nl = t >> 4, j = t & 15;
    float acc = bo[j];
    #pragma unroll 8
    for (int c = 0; c < F_IN; ++c)
        acc = fmaf(XH[nl][c], WoS[c * 16 + j], acc);
    out[(size_t)(q0 + nl) * 16 + j] = acc;
}

// ---------------------------------------------------------------------------
extern "C" void kernel_launch(void* const* d_in, const int* in_sizes, int n_in,
                              void* d_out, int out_size, void* d_ws, size_t ws_size,
                              hipStream_t stream) {
    const float* queries  = (const float*)d_in[0];
    const float* keys     = (const float*)d_in[1];
    const float* values   = (const float*)d_in[2];
    const float* presence = (const float*)d_in[3];
    const float* Wq = (const float*)d_in[4];
    const float* bq = (const float*)d_in[5];
    const float* Wk = (const float*)d_in[6];
    const float* bk = (const float*)d_in[7];
    const float* Wv = (const float*)d_in[8];
    const float* bv = (const float*)d_in[9];
    const float* Wo = (const float*)d_in[10];
    const float* bo = (const float*)d_in[11];
    float* out = (float*)d_out;

    int*   wsi = (int*)d_ws;
    float* wsf = (float*)d_ws;

    compute_head<<<1, 256, 0, stream>>>(values, presence, Wv, bv, Wo, bo, wsi, wsf);
    write_out<<<NQ / 16, 256, 0, stream>>>(
        queries, keys, values, Wq, bq, Wk, bk, Wv, bv, Wo, bo, wsi, wsf, out);
}

// Round 15
// 13.226 us; speedup vs baseline: 3.4992x; 1.0913x over previous
//
#include <hip/hip_runtime.h>
#include <hip/hip_bf16.h>

#define F_IN 256
#define NQ   4096
#define NK   4096
#define MAXC 16

// ---------------------------------------------------------------------------
// Round 15: single-dispatch version. Launch overhead (~5-7us/dispatch)
// dominates; the compute is ~0.1us. Every block redundantly computes the
// rank-1 result rS[16] (presence argmax is provably one-hot for f32 data:
// mask gaps >= 6e24 >> any qk + exp range), then stores its 16 rows.
// Redundant cost per block: ~288 KB of L2/L3-resident reads (Wv+Wo+presence)
// and 256+16 FMAs/thread -- cheaper than a second dispatch.
// C>1 exact-tie fallback (softmax over tied keys) retained for completeness.
// ---------------------------------------------------------------------------
__global__ __launch_bounds__(256) void attn_fused_onehot(
    const float* __restrict__ queries, const float* __restrict__ keys,
    const float* __restrict__ values,  const float* __restrict__ presence,
    const float* __restrict__ Wq, const float* __restrict__ bq,
    const float* __restrict__ Wk, const float* __restrict__ bk,
    const float* __restrict__ Wv, const float* __restrict__ bv,
    const float* __restrict__ Wo, const float* __restrict__ bo,
    float* __restrict__ out)
{
    const int t  = threadIdx.x;
    const int q0 = blockIdx.x * 16;

    __shared__ float redA[256];
    __shared__ float hvS[256];
    __shared__ float rSS[16];
    __shared__ float XH[16][260];
    __shared__ float WoS[4096];
    __shared__ int   candS[MAXC];
    __shared__ int   ncandS;
    __shared__ float pmaxS;

    // ---- presence: one register pass (float4), max-reduce ----
    float4 pv[4];
    {
        const float4* p4 = reinterpret_cast<const float4*>(presence);
        float mx = -1e30f;
        #pragma unroll
        for (int i = 0; i < 4; ++i) {
            pv[i] = p4[i * 256 + t];
            mx = fmaxf(mx, fmaxf(fmaxf(pv[i].x, pv[i].y), fmaxf(pv[i].z, pv[i].w)));
        }
        redA[t] = mx;
    }
    __syncthreads();
    for (int s = 128; s > 0; s >>= 1) {
        if (t < s) redA[t] = fmaxf(redA[t], redA[t + s]);
        __syncthreads();
    }
    if (t == 0) { pmaxS = redA[0]; ncandS = 0; }
    __syncthreads();
    const float pmax = pmaxS;

    // ---- exact-tie candidate set from registers ----
    #pragma unroll
    for (int i = 0; i < 4; ++i) {
        const int base = (i * 256 + t) * 4;
        const float e[4] = {pv[i].x, pv[i].y, pv[i].z, pv[i].w};
        #pragma unroll
        for (int j = 0; j < 4; ++j) {
            if (e[j] == pmax) {
                int slot = atomicAdd(&ncandS, 1);
                if (slot < MAXC) candS[slot] = base + j;
            }
        }
    }
    __syncthreads();
    const int C = ncandS < MAXC ? ncandS : MAXC;
    if (t == 0 && C > 1) {
        for (int a = 0; a < C; ++a)
            for (int b = a + 1; b < C; ++b)
                if (candS[b] < candS[a]) { int tmp = candS[a]; candS[a] = candS[b]; candS[b] = tmp; }
    }
    __syncthreads();

    if (C == 1) {
        // ---- live path: weight exactly 1.0; q/k projections cancel ----
        const int k = candS[0];
        // hv[t] = bv[t] + values[k,:] @ Wv[:,t]  (4-way split accumulators;
        // same order as round 14's verified bit-exact path)
        {
            const float* vrow = &values[(size_t)k * F_IN];
            float a0 = 0.f, a1 = 0.f, a2 = 0.f, a3 = 0.f;
            #pragma unroll 4
            for (int c = 0; c < F_IN; c += 4) {
                a0 = fmaf(vrow[c + 0], Wv[(size_t)(c + 0) * F_IN + t], a0);
                a1 = fmaf(vrow[c + 1], Wv[(size_t)(c + 1) * F_IN + t], a1);
                a2 = fmaf(vrow[c + 2], Wv[(size_t)(c + 2) * F_IN + t], a2);
                a3 = fmaf(vrow[c + 3], Wv[(size_t)(c + 3) * F_IN + t], a3);
            }
            hvS[t] = bv[t] + ((a0 + a1) + (a2 + a3));
        }
        __syncthreads();

        // rS[j] = bo[j] + sum_f hvS[f] * Wo[f][j]  (16 f-groups in parallel)
        {
            const int j = t & 15, g = t >> 4;
            float part = 0.f;
            #pragma unroll
            for (int f = g * 16; f < g * 16 + 16; ++f)
                part = fmaf(hvS[f], Wo[(size_t)f * 16 + j], part);
            redA[t] = part;
        }
        __syncthreads();
        for (int s = 128; s >= 16; s >>= 1) {
            if (t < s) redA[t] += redA[t + s];
            __syncthreads();
        }
        if (t < 16) rSS[t] = redA[t] + bo[t];
        __syncthreads();

        out[(size_t)q0 * 16 + t] = rSS[t & 15];
        return;
    }

    // ======================= general fallback (C > 1) =======================
    const int h  = t >> 4;
    const int qi = t & 15;

    for (int i = t; i < 1024; i += 256)
        *reinterpret_cast<float4*>(&WoS[i * 4]) =
            *reinterpret_cast<const float4*>(&Wo[i * 4]);
    __syncthreads();

    float qr[16];
    #pragma unroll
    for (int d = 0; d < 16; ++d) qr[d] = bq[h * 16 + d];
    for (int c = 0; c < F_IN; ++c) {
        const float x = queries[(size_t)(q0 + qi) * F_IN + c];
        const float* wr = &Wq[(size_t)c * F_IN + h * 16];
        #pragma unroll
        for (int d = 0; d < 16; ++d) qr[d] = fmaf(x, wr[d], qr[d]);
    }

    float sarr[MAXC];
    for (int ci = 0; ci < C; ++ci) {
        const int k = candS[ci];
        float kr[16];
        #pragma unroll
        for (int d = 0; d < 16; ++d) kr[d] = bk[h * 16 + d];
        for (int c = 0; c < F_IN; ++c) {
            const float x = keys[(size_t)k * F_IN + c];
            const float* wr = &Wk[(size_t)c * F_IN + h * 16];
            #pragma unroll
            for (int d = 0; d < 16; ++d) kr[d] = fmaf(x, wr[d], kr[d]);
        }
        float qk = 0.f;
        #pragma unroll
        for (int d = 0; d < 16; ++d) qk = fmaf(qr[d], kr[d], qk);
        sarr[ci] = qk * 0.25f;
    }
    float m = -INFINITY;
    for (int ci = 0; ci < C; ++ci) m = fmaxf(m, sarr[ci]);
    float wgt[MAXC];
    float l = 0.f;
    for (int ci = 0; ci < C; ++ci) { wgt[ci] = __expf(sarr[ci] - m); l += wgt[ci]; }
    const float inv = 1.0f / l;

    float o[16] = {};
    for (int ci = 0; ci < C; ++ci) {
        const int k = candS[ci];
        float vr[16];
        #pragma unroll
        for (int d = 0; d < 16; ++d) vr[d] = bv[h * 16 + d];
        for (int c = 0; c < F_IN; ++c) {
            const float x = values[(size_t)k * F_IN + c];
            const float* wr = &Wv[(size_t)c * F_IN + h * 16];
            #pragma unroll
            for (int d = 0; d < 16; ++d) vr[d] = fmaf(x, wr[d], vr[d]);
        }
        const float ww = wgt[ci] * inv;
        #pragma unroll
        for (int d = 0; d < 16; ++d) o[d] = fmaf(ww, vr[d], o[d]);
    }

    __syncthreads();
    #pragma unroll
    for (int d = 0; d < 16; ++d) XH[qi][h * 16 + d] = o[d];
    __syncthreads();

    const int nl = t >> 4, j = t & 15;
    float acc = bo[j];
    #pragma unroll 8
    for (int c = 0; c < F_IN; ++c)
        acc = fmaf(XH[nl][c], WoS[c * 16 + j], acc);
    out[(size_t)(q0 + nl) * 16 + j] = acc;
}

// ---------------------------------------------------------------------------
extern "C" void kernel_launch(void* const* d_in, const int* in_sizes, int n_in,
                              void* d_out, int out_size, void* d_ws, size_t ws_size,
                              hipStream_t stream) {
    const float* queries  = (const float*)d_in[0];
    const float* keys     = (const float*)d_in[1];
    const float* values   = (const float*)d_in[2];
    const float* presence = (const float*)d_in[3];
    const float* Wq = (const float*)d_in[4];
    const float* bq = (const float*)d_in[5];
    const float* Wk = (const float*)d_in[6];
    const float* bk = (const float*)d_in[7];
    const float* Wv = (const float*)d_in[8];
    const float* bv = (const float*)d_in[9];
    const float* Wo = (const float*)d_in[10];
    const float* bo = (const float*)d_in[11];
    float* out = (float*)d_out;

    attn_fused_onehot<<<NQ / 16, 256, 0, stream>>>(
        queries, keys, values, presence, Wq, bq, Wk, bk, Wv, bv, Wo, bo, out);
}